// Round 17
// baseline (123.507 us; speedup 1.0000x reference)
//
#include <hip/hip_runtime.h>
#include <hip/hip_fp16.h>

#define DIN 256
#define DOUT 64
#define BUCKET_BITS 14
#define BUCKET (1 << BUCKET_BITS)   // 16384 nodes per bucket; LDS word array packs 2 buckets
#define CHUNKS 64
#define BM 128

using half8 = __attribute__((ext_vector_type(8))) _Float16;
using f32x4 = __attribute__((ext_vector_type(4))) float;

// ---------------- histogram (packed-pair) + epack production (R12 verbatim) ----------------
__global__ __launch_bounds__(256) void hist_kernel(
    const int* __restrict__ src, const int* __restrict__ dst,
    unsigned short* __restrict__ part, unsigned int* __restrict__ epack,
    int n_nodes, int n_edges, int n_pad)
{
    __shared__ unsigned int cnt[BUCKET];
    const int c = blockIdx.x, p = blockIdx.y, a = blockIdx.z;
    const int* __restrict__ idx = a ? dst : src;
    const int pairbase = p << 15;
    const int tid = threadIdx.x;

    for (int i = tid; i < BUCKET; i += 256) cnt[i] = 0;
    __syncthreads();

    const int ebeg = (int)((long long)n_edges * c / CHUNKS);
    const int eend = (int)((long long)n_edges * (c + 1) / CHUNKS);
    const int len = eend - ebeg;
    const int nvec = len >> 2;
    const int4* idx4 = (const int4*)(idx + ebeg);
    for (int q = tid; q < nvec; q += 256) {
        int4 e4 = idx4[q];
        unsigned u0 = (unsigned)(e4.x - pairbase);
        unsigned u1 = (unsigned)(e4.y - pairbase);
        unsigned u2 = (unsigned)(e4.z - pairbase);
        unsigned u3 = (unsigned)(e4.w - pairbase);
        if (u0 < 32768u) atomicAdd(&cnt[u0 & (BUCKET - 1)], 1u << ((u0 >> BUCKET_BITS) << 4));
        if (u1 < 32768u) atomicAdd(&cnt[u1 & (BUCKET - 1)], 1u << ((u1 >> BUCKET_BITS) << 4));
        if (u2 < 32768u) atomicAdd(&cnt[u2 & (BUCKET - 1)], 1u << ((u2 >> BUCKET_BITS) << 4));
        if (u3 < 32768u) atomicAdd(&cnt[u3 & (BUCKET - 1)], 1u << ((u3 >> BUCKET_BITS) << 4));
    }
    for (int e = ebeg + (nvec << 2) + tid; e < eend; e += 256) {
        unsigned u = (unsigned)(idx[e] - pairbase);
        if (u < 32768u) atomicAdd(&cnt[u & (BUCKET - 1)], 1u << ((u >> BUCKET_BITS) << 4));
    }

    if (a == 1) {
        const int half0 = ((len >> 1) + 3) & ~3;
        const int pb = ebeg + (p ? half0 : 0);
        const int pe = p ? eend : (ebeg + half0);
        const int nv2 = (pe - pb) >> 2;
        const int4* s4 = (const int4*)(src + pb);
        const int4* d4 = (const int4*)(dst + pb);
        uint4* o4 = (uint4*)(epack + pb);
        for (int q = tid; q < nv2; q += 256) {
            int4 s = s4[q];
            int4 d = d4[q];
            uint4 o;
            o.x = ((unsigned)d.x << 16) | (unsigned)s.x;
            o.y = ((unsigned)d.y << 16) | (unsigned)s.y;
            o.z = ((unsigned)d.z << 16) | (unsigned)s.z;
            o.w = ((unsigned)d.w << 16) | (unsigned)s.w;
            o4[q] = o;
        }
        for (int e = pb + (nv2 << 2) + tid; e < pe; e += 256)
            epack[e] = ((unsigned)dst[e] << 16) | (unsigned)src[e];
    }
    __syncthreads();

    unsigned short* row = part + (size_t)(a * CHUNKS + c) * n_pad;
    for (int w2 = tid; w2 < BUCKET; w2 += 256) {
        unsigned v = cnt[w2];
        int n0 = pairbase + w2;
        int n1 = pairbase + BUCKET + w2;
        if (n0 < n_nodes) row[n0] = (unsigned short)(v & 0xffffu);
        if (n1 < n_nodes) row[n1] = (unsigned short)(v >> 16);
    }
}

// ---------------- reduce_pair: 2 nodes/thread via u32; nsf, indeg, in-place prefix, bsum; +convW ----------------
__global__ __launch_bounds__(256) void reduce_pair_kernel(
    unsigned short* __restrict__ part, float* __restrict__ nsf,
    int* __restrict__ indeg, int* __restrict__ bsum, int n_nodes, int n_pad,
    int nb, const float* __restrict__ W, unsigned short* __restrict__ w16t)
{
    if (blockIdx.x >= nb) {
        int idx = (blockIdx.x - nb) * 256 + threadIdx.x;   // 0..16383
        int n = idx & 63, k = idx >> 6;
        __half v = __float2half(W[k * DOUT + n]);
        w16t[n * DIN + k] = *(unsigned short*)&v;
        return;
    }
    __shared__ int red[4];
    const int t = threadIdx.x;
    const int i0 = blockIdx.x * 512 + t * 2;

    int run0 = 0, run1 = 0;
    if (i0 < n_nodes) {
        int sum0 = 0, sum1 = 0;
        #pragma unroll
        for (int c = 0; c < CHUNKS; ++c) {
            unsigned w = *(const unsigned*)(part + (size_t)c * n_pad + i0);
            sum0 += (int)(w & 0xffffu);
            sum1 += (int)(w >> 16);
        }
        nsf[i0] = rsqrtf(fmaxf((float)sum0, 1.0f));
        const bool ok1 = (i0 + 1 < n_nodes);
        if (ok1) nsf[i0 + 1] = rsqrtf(fmaxf((float)sum1, 1.0f));
        #pragma unroll
        for (int c = 0; c < CHUNKS; ++c) {
            unsigned* pw = (unsigned*)(part + (size_t)(CHUNKS + c) * n_pad + i0);
            unsigned w = *pw;
            *pw = (unsigned)run0 | ((unsigned)run1 << 16);   // exclusive prefix for both nodes
            run0 += (int)(w & 0xffffu);
            run1 += (int)(w >> 16);
        }
        if (!ok1) run1 = 0;
        indeg[i0] = run0;
        if (ok1) indeg[i0 + 1] = run1;
    }

    int v = run0 + run1;
    #pragma unroll
    for (int off = 32; off >= 1; off >>= 1)
        v += __shfl_down(v, off, 64);
    if ((t & 63) == 0) red[t >> 6] = v;
    __syncthreads();
    if (t == 0)
        bsum[blockIdx.x] = red[0] + red[1] + red[2] + red[3];
}

// ---------------- emit_pair: redundant bsum scan + block-local pair scan -> rowptr ----------------
__global__ __launch_bounds__(256) void emit_pair_kernel(
    const int* __restrict__ indeg, const int* __restrict__ bsum,
    int* __restrict__ rowptr, int n, int n_edges, int nb)
{
    __shared__ int bs[128];
    __shared__ int s[256];
    const int t = threadIdx.x;
    const int i0 = blockIdx.x * 512 + t * 2;

    if (t < 128) bs[t] = (t < nb) ? bsum[t] : 0;
    __syncthreads();
    for (int off = 1; off < 128; off <<= 1) {
        int u = 0;
        if (t < 128 && t >= off) u = bs[t - off];
        __syncthreads();
        if (t < 128 && t >= off) bs[t] += u;
        __syncthreads();
    }
    const int boff_blk = (blockIdx.x == 0) ? 0 : bs[blockIdx.x - 1];

    int run0 = 0, run1 = 0;
    if (i0 < n) {
        int2 d = *(const int2*)(indeg + i0);   // i0 even; indeg padded safe (n_pad > n)
        run0 = d.x;
        run1 = (i0 + 1 < n) ? d.y : 0;
    }
    const int tot = run0 + run1;

    s[t] = tot;
    __syncthreads();
    for (int off = 1; off < 256; off <<= 1) {
        int u = 0;
        if (t >= off) u = s[t - off];
        __syncthreads();
        if (t >= off) s[t] += u;
        __syncthreads();
    }
    const int excl = boff_blk + s[t] - tot;
    if (i0 < n) {
        rowptr[i0] = excl;
        if (i0 + 1 < n) rowptr[i0 + 1] = excl + run0;
    }
    if (i0 == 0) rowptr[n] = n_edges;
}

// ---------------- CSR fill via LDS cursor multisplit, packed edges (R12 verbatim) ----------------
__global__ __launch_bounds__(256) void fill_kernel(
    const unsigned int* __restrict__ epack,
    const unsigned short* __restrict__ part, const int* __restrict__ rowptr,
    unsigned short* __restrict__ col, int n_nodes, int n_edges, int n_pad)
{
    __shared__ int cur[BUCKET];
    const int c = blockIdx.x, b = blockIdx.y;
    const int base = b << BUCKET_BITS;
    const int lim = min(BUCKET, n_nodes - base);

    const unsigned short* prow = part + (size_t)(CHUNKS + c) * n_pad + base;
    const int* rp = rowptr + base;
    for (int i = threadIdx.x; i < lim; i += 256)
        cur[i] = rp[i] + (int)prow[i];
    __syncthreads();

    const int ebeg = (int)((long long)n_edges * c / CHUNKS);
    const int eend = (int)((long long)n_edges * (c + 1) / CHUNKS);
    const int nvec = (eend - ebeg) >> 2;
    const uint4* pk4 = (const uint4*)(epack + ebeg);
    for (int q = threadIdx.x; q < nvec; q += 256) {
        uint4 e4 = pk4[q];
        unsigned v0 = (e4.x >> 16) - (unsigned)base;
        unsigned v1 = (e4.y >> 16) - (unsigned)base;
        unsigned v2 = (e4.z >> 16) - (unsigned)base;
        unsigned v3 = (e4.w >> 16) - (unsigned)base;
        if (v0 < (unsigned)BUCKET) col[atomicAdd(&cur[v0], 1)] = (unsigned short)(e4.x & 0xffffu);
        if (v1 < (unsigned)BUCKET) col[atomicAdd(&cur[v1], 1)] = (unsigned short)(e4.y & 0xffffu);
        if (v2 < (unsigned)BUCKET) col[atomicAdd(&cur[v2], 1)] = (unsigned short)(e4.z & 0xffffu);
        if (v3 < (unsigned)BUCKET) col[atomicAdd(&cur[v3], 1)] = (unsigned short)(e4.w & 0xffffu);
    }
    for (int e = ebeg + (nvec << 2) + threadIdx.x; e < eend; e += 256) {
        unsigned pk = epack[e];
        unsigned v = (pk >> 16) - (unsigned)base;
        if (v < (unsigned)BUCKET) col[atomicAdd(&cur[v], 1)] = (unsigned short)(pk & 0xffffu);
    }
}

// ---------------- MFMA GEMM, direct-global A: h (two fp16 planes) = (x * ns) @ W ----------------
// A fragment of lane (l16,kg) = x[row][kk*32 + kg*8 .. +8] -- 32 contiguous bytes, no LDS round-trip.
// B staged once in swizzled LDS (32 KB); no __syncthreads in the K loop.
__global__ __launch_bounds__(256) void gemm_mfma_kernel(
    const float* __restrict__ x, const unsigned short* __restrict__ w16t,
    const float* __restrict__ nsf, __half* __restrict__ h,
    int n_nodes, size_t plane_elems)
{
    __shared__ unsigned char Bbuf[64 * 512];   // [64 cols][256 halves = 512 B], swizzled

    const int tid = threadIdx.x;
    const int r0 = blockIdx.x * BM;
    const int w = tid >> 6;
    const int lane = tid & 63;
    const int l16 = lane & 15;
    const int kg = lane >> 4;

    // stage B once
    {
        const uint4* srcB = (const uint4*)w16t;
        for (int u = tid; u < 64 * 32; u += 256) {
            int c = u >> 5, q = u & 31;
            uint4 v = srcB[u];
            int byte = (c << 9) + (q << 4);
            byte ^= ((c & 7) << 4);
            *(uint4*)(Bbuf + byte) = v;
        }
    }
    __syncthreads();

    const int row0 = r0 + (w << 5) + l16;   // rt = 0
    const int row1 = row0 + 16;             // rt = 1
    const bool ok0 = row0 < n_nodes;
    const bool ok1 = row1 < n_nodes;
    const float* xr0 = x + (size_t)row0 * DIN + (kg << 3);
    const float* xr1 = x + (size_t)row1 * DIN + (kg << 3);

    f32x4 acc[2][4] = {{{0.f,0.f,0.f,0.f}}};
    const float4 z4 = make_float4(0.f, 0.f, 0.f, 0.f);

    #pragma unroll
    for (int kk = 0; kk < 8; ++kk) {
        // A fragments direct from global: 8 consecutive f32 -> 8 halves
        float4 v00 = ok0 ? *(const float4*)(xr0 + kk * 32)     : z4;
        float4 v01 = ok0 ? *(const float4*)(xr0 + kk * 32 + 4) : z4;
        float4 v10 = ok1 ? *(const float4*)(xr1 + kk * 32)     : z4;
        float4 v11 = ok1 ? *(const float4*)(xr1 + kk * 32 + 4) : z4;

        union { half8 h8; __half2 h2[4]; } ua0, ua1;
        ua0.h2[0] = __floats2half2_rn(v00.x, v00.y);
        ua0.h2[1] = __floats2half2_rn(v00.z, v00.w);
        ua0.h2[2] = __floats2half2_rn(v01.x, v01.y);
        ua0.h2[3] = __floats2half2_rn(v01.z, v01.w);
        ua1.h2[0] = __floats2half2_rn(v10.x, v10.y);
        ua1.h2[1] = __floats2half2_rn(v10.z, v10.w);
        ua1.h2[2] = __floats2half2_rn(v11.x, v11.y);
        ua1.h2[3] = __floats2half2_rn(v11.z, v11.w);

        half8 b[4];
        #pragma unroll
        for (int ct = 0; ct < 4; ++ct) {
            int c = (ct << 4) + l16;
            int byte = (c << 9) + (kk << 6) + (kg << 4);
            byte ^= ((c & 7) << 4);
            b[ct] = *(const half8*)(Bbuf + byte);
        }
        #pragma unroll
        for (int ct = 0; ct < 4; ++ct) {
            acc[0][ct] = __builtin_amdgcn_mfma_f32_16x16x32_f16(ua0.h8, b[ct], acc[0][ct], 0, 0, 0);
            acc[1][ct] = __builtin_amdgcn_mfma_f32_16x16x32_f16(ua1.h8, b[ct], acc[1][ct], 0, 0, 0);
        }
    }

    #pragma unroll
    for (int rt = 0; rt < 2; ++rt) {
        #pragma unroll
        for (int reg = 0; reg < 4; ++reg) {
            int grow = r0 + (w << 5) + (rt << 4) + (kg << 2) + reg;
            if (grow < n_nodes) {
                float ns = nsf[grow];
                #pragma unroll
                for (int ct = 0; ct < 4; ++ct) {
                    int colp = ((ct & 1) << 4) + l16;
                    __half* hp = h + (size_t)(ct >> 1) * plane_elems + ((size_t)grow << 5) + colp;
                    *hp = __float2half(acc[rt][ct][reg] * ns);
                }
            }
        }
    }
}

// ---------------- gather ONE 32-col plane (R12 verbatim: 8 lanes/edge, uint2, unroll 2) ----------------
__global__ __launch_bounds__(256) void gather_kernel(
    const __half* __restrict__ h, const int* __restrict__ rowptr,
    const unsigned short* __restrict__ col, const float* __restrict__ bias,
    float* __restrict__ out, int n_nodes, size_t plane_elems, int plane)
{
    int wid = (blockIdx.x * blockDim.x + threadIdx.x) >> 6;
    int lane = threadIdx.x & 63;
    if (wid >= n_nodes) return;
    const int g = lane >> 3, l8 = lane & 7;

    const int beg = rowptr[wid];
    const int end = rowptr[wid + 1];
    const int deg = end - beg;

    const char* hbase = (const char*)(h + (size_t)plane * plane_elems) + (l8 << 3);

    float4 acc = make_float4(0.f, 0.f, 0.f, 0.f);
    #pragma unroll 2
    for (int i = beg + g; i < end; i += 8) {
        int s = col[i];
        uint2 v = *(const uint2*)(hbase + ((size_t)s << 6));
        __half2 p0 = *(__half2*)&v.x;
        __half2 p1 = *(__half2*)&v.y;
        float2 a = __half22float2(p0);
        float2 b2 = __half22float2(p1);
        acc.x += a.x; acc.y += a.y; acc.z += b2.x; acc.w += b2.y;
    }

    #pragma unroll
    for (int d = 8; d <= 32; d <<= 1) {
        acc.x += __shfl_xor(acc.x, d, 64);
        acc.y += __shfl_xor(acc.y, d, 64);
        acc.z += __shfl_xor(acc.z, d, 64);
        acc.w += __shfl_xor(acc.w, d, 64);
    }

    if (g == 0) {
        float nd = rsqrtf(fmaxf((float)deg, 1.0f));
        int c0 = (plane << 5) + (l8 << 2);
        float4 bb = *(const float4*)(&bias[c0]);
        float4 o;
        o.x = fmaxf(fmaf(acc.x, nd, bb.x), 0.f);
        o.y = fmaxf(fmaf(acc.y, nd, bb.y), 0.f);
        o.z = fmaxf(fmaf(acc.z, nd, bb.z), 0.f);
        o.w = fmaxf(fmaf(acc.w, nd, bb.w), 0.f);
        *(float4*)(&out[((size_t)wid << 6) + c0]) = o;
    }
}

extern "C" void kernel_launch(void* const* d_in, const int* in_sizes, int n_in,
                              void* d_out, int out_size, void* d_ws, size_t ws_size,
                              hipStream_t stream) {
    const float* x   = (const float*)d_in[0];
    const float* W   = (const float*)d_in[1];
    const float* b   = (const float*)d_in[2];
    const int*   src = (const int*)d_in[3];
    const int*   dst = (const int*)d_in[4];
    float* out = (float*)d_out;

    const int n_nodes = in_sizes[0] / DIN;   // 50000
    const int n_edges = in_sizes[3];         // 800000
    const int nb = (n_nodes + 511) / 512;                        // 98
    const int nbuck = (n_nodes + BUCKET - 1) >> BUCKET_BITS;     // 4
    const int npair = (nbuck + 1) >> 1;                          // 2
    const int n_pad = ((n_nodes + 63) / 64) * 64;                // 50048
    const size_t plane_elems = (size_t)n_pad * 32;               // halves per plane

    // workspace layout
    float* nsf  = (float*)d_ws;                 // n
    int* indeg  = (int*)(nsf + n_nodes);        // n_pad (pair reads safe)
    int* rowptr = indeg + n_pad;                // n+1
    int* bsum   = rowptr + n_nodes + 1;         // 128
    unsigned short* w16t = (unsigned short*)(bsum + 128);    // 16384 u16
    size_t off = (size_t)((char*)(w16t + 16384) - (char*)d_ws);
    off = (off + 63) / 64 * 64;
    unsigned int* epack = (unsigned int*)((char*)d_ws + off);        // n_edges u32
    off += (((size_t)n_edges * 4 + 63) / 64) * 64;
    unsigned short* col = (unsigned short*)((char*)d_ws + off);      // n_edges u16
    off += (((size_t)n_edges * 2 + 63) / 64) * 64;
    unsigned short* part = (unsigned short*)((char*)d_ws + off);     // 2*CHUNKS*n_pad u16
    off += (((size_t)2 * CHUNKS * n_pad * 2 + 63) / 64) * 64;
    __half* h = (__half*)((char*)d_ws + off);                        // 2 planes x n_pad x 32

    hist_kernel<<<dim3(CHUNKS, npair, 2), 256, 0, stream>>>(src, dst, part, epack, n_nodes, n_edges, n_pad);
    reduce_pair_kernel<<<nb + 64, 256, 0, stream>>>(part, nsf, indeg, bsum, n_nodes, n_pad, nb, W, w16t);
    emit_pair_kernel<<<nb, 256, 0, stream>>>(indeg, bsum, rowptr, n_nodes, n_edges, nb);
    fill_kernel<<<dim3(CHUNKS, nbuck), 256, 0, stream>>>(epack, part, rowptr, col, n_nodes, n_edges, n_pad);
    gemm_mfma_kernel<<<(n_nodes + BM - 1) / BM, 256, 0, stream>>>(x, w16t, nsf, h, n_nodes, plane_elems);
    gather_kernel<<<((size_t)n_nodes * 64 + 255) / 256, 256, 0, stream>>>(h, rowptr, col, b, out, n_nodes, plane_elems, 0);
    gather_kernel<<<((size_t)n_nodes * 64 + 255) / 256, 256, 0, stream>>>(h, rowptr, col, b, out, n_nodes, plane_elems, 1);
}

// Round 18
// 107.137 us; speedup vs baseline: 1.1528x; 1.1528x over previous
//
#include <hip/hip_runtime.h>
#include <hip/hip_fp16.h>

#define DIN 256
#define DOUT 64
#define BUCKET_BITS 14
#define BUCKET (1 << BUCKET_BITS)   // 16384 nodes per bucket; LDS word array packs 2 buckets
#define CHUNKS 64
#define BM 128

using half8 = __attribute__((ext_vector_type(8))) _Float16;
using f32x4 = __attribute__((ext_vector_type(4))) float;

// ---------------- histogram (packed-pair) + epack production ----------------
__global__ __launch_bounds__(256) void hist_kernel(
    const int* __restrict__ src, const int* __restrict__ dst,
    unsigned short* __restrict__ part, unsigned int* __restrict__ epack,
    int n_nodes, int n_edges, int n_pad)
{
    __shared__ unsigned int cnt[BUCKET];
    const int c = blockIdx.x, p = blockIdx.y, a = blockIdx.z;
    const int* __restrict__ idx = a ? dst : src;
    const int pairbase = p << 15;
    const int tid = threadIdx.x;

    for (int i = tid; i < BUCKET; i += 256) cnt[i] = 0;
    __syncthreads();

    const int ebeg = (int)((long long)n_edges * c / CHUNKS);
    const int eend = (int)((long long)n_edges * (c + 1) / CHUNKS);
    const int len = eend - ebeg;
    const int nvec = len >> 2;
    const int4* idx4 = (const int4*)(idx + ebeg);
    for (int q = tid; q < nvec; q += 256) {
        int4 e4 = idx4[q];
        unsigned u0 = (unsigned)(e4.x - pairbase);
        unsigned u1 = (unsigned)(e4.y - pairbase);
        unsigned u2 = (unsigned)(e4.z - pairbase);
        unsigned u3 = (unsigned)(e4.w - pairbase);
        if (u0 < 32768u) atomicAdd(&cnt[u0 & (BUCKET - 1)], 1u << ((u0 >> BUCKET_BITS) << 4));
        if (u1 < 32768u) atomicAdd(&cnt[u1 & (BUCKET - 1)], 1u << ((u1 >> BUCKET_BITS) << 4));
        if (u2 < 32768u) atomicAdd(&cnt[u2 & (BUCKET - 1)], 1u << ((u2 >> BUCKET_BITS) << 4));
        if (u3 < 32768u) atomicAdd(&cnt[u3 & (BUCKET - 1)], 1u << ((u3 >> BUCKET_BITS) << 4));
    }
    for (int e = ebeg + (nvec << 2) + tid; e < eend; e += 256) {
        unsigned u = (unsigned)(idx[e] - pairbase);
        if (u < 32768u) atomicAdd(&cnt[u & (BUCKET - 1)], 1u << ((u >> BUCKET_BITS) << 4));
    }

    if (a == 1) {
        const int half0 = ((len >> 1) + 3) & ~3;
        const int pb = ebeg + (p ? half0 : 0);
        const int pe = p ? eend : (ebeg + half0);
        const int nv2 = (pe - pb) >> 2;
        const int4* s4 = (const int4*)(src + pb);
        const int4* d4 = (const int4*)(dst + pb);
        uint4* o4 = (uint4*)(epack + pb);
        for (int q = tid; q < nv2; q += 256) {
            int4 s = s4[q];
            int4 d = d4[q];
            uint4 o;
            o.x = ((unsigned)d.x << 16) | (unsigned)s.x;
            o.y = ((unsigned)d.y << 16) | (unsigned)s.y;
            o.z = ((unsigned)d.z << 16) | (unsigned)s.z;
            o.w = ((unsigned)d.w << 16) | (unsigned)s.w;
            o4[q] = o;
        }
        for (int e = pb + (nv2 << 2) + tid; e < pe; e += 256)
            epack[e] = ((unsigned)dst[e] << 16) | (unsigned)src[e];
    }
    __syncthreads();

    unsigned short* row = part + (size_t)(a * CHUNKS + c) * n_pad;
    for (int w2 = tid; w2 < BUCKET; w2 += 256) {
        unsigned v = cnt[w2];
        int n0 = pairbase + w2;
        int n1 = pairbase + BUCKET + w2;
        if (n0 < n_nodes) row[n0] = (unsigned short)(v & 0xffffu);
        if (n1 < n_nodes) row[n1] = (unsigned short)(v >> 16);
    }
}

// ---------------- reduce_pair: 2 nodes/thread via u32; nsf, indeg, in-place prefix, bsum; +convW ----------------
__global__ __launch_bounds__(256) void reduce_pair_kernel(
    unsigned short* __restrict__ part, float* __restrict__ nsf,
    int* __restrict__ indeg, int* __restrict__ bsum, int n_nodes, int n_pad,
    int nb, const float* __restrict__ W, unsigned short* __restrict__ w16t)
{
    if (blockIdx.x >= nb) {
        int idx = (blockIdx.x - nb) * 256 + threadIdx.x;   // 0..16383
        int n = idx & 63, k = idx >> 6;
        __half v = __float2half(W[k * DOUT + n]);
        w16t[n * DIN + k] = *(unsigned short*)&v;
        return;
    }
    __shared__ int red[4];
    const int t = threadIdx.x;
    const int i0 = blockIdx.x * 512 + t * 2;

    int run0 = 0, run1 = 0;
    if (i0 < n_nodes) {
        int sum0 = 0, sum1 = 0;
        #pragma unroll
        for (int c = 0; c < CHUNKS; ++c) {
            unsigned w = *(const unsigned*)(part + (size_t)c * n_pad + i0);
            sum0 += (int)(w & 0xffffu);
            sum1 += (int)(w >> 16);
        }
        nsf[i0] = rsqrtf(fmaxf((float)sum0, 1.0f));
        const bool ok1 = (i0 + 1 < n_nodes);
        if (ok1) nsf[i0 + 1] = rsqrtf(fmaxf((float)sum1, 1.0f));
        #pragma unroll
        for (int c = 0; c < CHUNKS; ++c) {
            unsigned* pw = (unsigned*)(part + (size_t)(CHUNKS + c) * n_pad + i0);
            unsigned w = *pw;
            *pw = (unsigned)run0 | ((unsigned)run1 << 16);   // exclusive prefix for both nodes
            run0 += (int)(w & 0xffffu);
            run1 += (int)(w >> 16);
        }
        if (!ok1) run1 = 0;
        indeg[i0] = run0;
        if (ok1) indeg[i0 + 1] = run1;
    }

    int v = run0 + run1;
    #pragma unroll
    for (int off = 32; off >= 1; off >>= 1)
        v += __shfl_down(v, off, 64);
    if ((t & 63) == 0) red[t >> 6] = v;
    __syncthreads();
    if (t == 0)
        bsum[blockIdx.x] = red[0] + red[1] + red[2] + red[3];
}

// ---------------- emit_pair: redundant bsum scan + block-local pair scan -> rowptr ----------------
__global__ __launch_bounds__(256) void emit_pair_kernel(
    const int* __restrict__ indeg, const int* __restrict__ bsum,
    int* __restrict__ rowptr, int n, int n_edges, int nb)
{
    __shared__ int bs[128];
    __shared__ int s[256];
    const int t = threadIdx.x;
    const int i0 = blockIdx.x * 512 + t * 2;

    if (t < 128) bs[t] = (t < nb) ? bsum[t] : 0;
    __syncthreads();
    for (int off = 1; off < 128; off <<= 1) {
        int u = 0;
        if (t < 128 && t >= off) u = bs[t - off];
        __syncthreads();
        if (t < 128 && t >= off) bs[t] += u;
        __syncthreads();
    }
    const int boff_blk = (blockIdx.x == 0) ? 0 : bs[blockIdx.x - 1];

    int run0 = 0, run1 = 0;
    if (i0 < n) {
        int2 d = *(const int2*)(indeg + i0);   // i0 even; indeg padded safe (n_pad > n)
        run0 = d.x;
        run1 = (i0 + 1 < n) ? d.y : 0;
    }
    const int tot = run0 + run1;

    s[t] = tot;
    __syncthreads();
    for (int off = 1; off < 256; off <<= 1) {
        int u = 0;
        if (t >= off) u = s[t - off];
        __syncthreads();
        if (t >= off) s[t] += u;
        __syncthreads();
    }
    const int excl = boff_blk + s[t] - tot;
    if (i0 < n) {
        rowptr[i0] = excl;
        if (i0 + 1 < n) rowptr[i0 + 1] = excl + run0;
    }
    if (i0 == 0) rowptr[n] = n_edges;
}

// ---------------- CSR fill via LDS cursor multisplit, reading packed edges (4 B/edge) ----------------
__global__ __launch_bounds__(256) void fill_kernel(
    const unsigned int* __restrict__ epack,
    const unsigned short* __restrict__ part, const int* __restrict__ rowptr,
    unsigned short* __restrict__ col, int n_nodes, int n_edges, int n_pad)
{
    __shared__ int cur[BUCKET];
    const int c = blockIdx.x, b = blockIdx.y;
    const int base = b << BUCKET_BITS;
    const int lim = min(BUCKET, n_nodes - base);

    const unsigned short* prow = part + (size_t)(CHUNKS + c) * n_pad + base;
    const int* rp = rowptr + base;
    for (int i = threadIdx.x; i < lim; i += 256)
        cur[i] = rp[i] + (int)prow[i];
    __syncthreads();

    const int ebeg = (int)((long long)n_edges * c / CHUNKS);
    const int eend = (int)((long long)n_edges * (c + 1) / CHUNKS);
    const int nvec = (eend - ebeg) >> 2;
    const uint4* pk4 = (const uint4*)(epack + ebeg);
    for (int q = threadIdx.x; q < nvec; q += 256) {
        uint4 e4 = pk4[q];
        unsigned v0 = (e4.x >> 16) - (unsigned)base;
        unsigned v1 = (e4.y >> 16) - (unsigned)base;
        unsigned v2 = (e4.z >> 16) - (unsigned)base;
        unsigned v3 = (e4.w >> 16) - (unsigned)base;
        if (v0 < (unsigned)BUCKET) col[atomicAdd(&cur[v0], 1)] = (unsigned short)(e4.x & 0xffffu);
        if (v1 < (unsigned)BUCKET) col[atomicAdd(&cur[v1], 1)] = (unsigned short)(e4.y & 0xffffu);
        if (v2 < (unsigned)BUCKET) col[atomicAdd(&cur[v2], 1)] = (unsigned short)(e4.z & 0xffffu);
        if (v3 < (unsigned)BUCKET) col[atomicAdd(&cur[v3], 1)] = (unsigned short)(e4.w & 0xffffu);
    }
    for (int e = ebeg + (nvec << 2) + threadIdx.x; e < eend; e += 256) {
        unsigned pk = epack[e];
        unsigned v = (pk >> 16) - (unsigned)base;
        if (v < (unsigned)BUCKET) col[atomicAdd(&cur[v], 1)] = (unsigned short)(pk & 0xffffu);
    }
}

// ---------------- MFMA GEMM (R12-proven LDS-staged A): h (two fp16 planes) = (x * ns) @ W ----------------
__global__ __launch_bounds__(256) void gemm_mfma_kernel(
    const float* __restrict__ x, const unsigned short* __restrict__ w16t,
    const float* __restrict__ nsf, __half* __restrict__ h,
    int n_nodes, size_t plane_elems)
{
    __shared__ unsigned char Abuf[BM * 128];   // [128 rows][64 halves = 128 B], swizzled
    __shared__ unsigned char Bbuf[64 * 512];   // [64 cols][256 halves = 512 B], swizzled

    const int tid = threadIdx.x;
    const int r0 = blockIdx.x * BM;
    const int w = tid >> 6;
    const int lane = tid & 63;
    const int l16 = lane & 15;
    const int kg = lane >> 4;

    {
        const uint4* srcB = (const uint4*)w16t;
        for (int u = tid; u < 64 * 32; u += 256) {
            int c = u >> 5, q = u & 31;
            uint4 v = srcB[u];
            int byte = (c << 9) + (q << 4);
            byte ^= ((c & 7) << 4);
            *(uint4*)(Bbuf + byte) = v;
        }
    }

    f32x4 acc[2][4] = {{{0.f,0.f,0.f,0.f}}};

    for (int k0 = 0; k0 < 4; ++k0) {
        if (k0) __syncthreads();
        for (int u = tid; u < BM * 16; u += 256) {
            int row = u >> 4, fq = u & 15;
            int grow = r0 + row;
            float4 v = make_float4(0.f, 0.f, 0.f, 0.f);
            if (grow < n_nodes)
                v = *(const float4*)(&x[(size_t)grow * DIN + (k0 << 6) + (fq << 2)]);
            __half2 p0 = __floats2half2_rn(v.x, v.y);
            __half2 p1 = __floats2half2_rn(v.z, v.w);
            uint2 wv;
            wv.x = *(unsigned int*)&p0;
            wv.y = *(unsigned int*)&p1;
            int byte = (row << 7) + (fq << 3);
            byte ^= ((row & 7) << 4);
            *(uint2*)(Abuf + byte) = wv;
        }
        __syncthreads();

        #pragma unroll
        for (int ks = 0; ks < 2; ++ks) {
            half8 a[2], b[4];
            #pragma unroll
            for (int rt = 0; rt < 2; ++rt) {
                int row = (w << 5) + (rt << 4) + l16;
                int byte = (row << 7) + (ks << 6) + (kg << 4);
                byte ^= ((row & 7) << 4);
                a[rt] = *(const half8*)(Abuf + byte);
            }
            #pragma unroll
            for (int ct = 0; ct < 4; ++ct) {
                int c = (ct << 4) + l16;
                int byte = (c << 9) + (k0 << 7) + (ks << 6) + (kg << 4);
                byte ^= ((c & 7) << 4);
                b[ct] = *(const half8*)(Bbuf + byte);
            }
            #pragma unroll
            for (int rt = 0; rt < 2; ++rt)
                #pragma unroll
                for (int ct = 0; ct < 4; ++ct)
                    acc[rt][ct] = __builtin_amdgcn_mfma_f32_16x16x32_f16(a[rt], b[ct], acc[rt][ct], 0, 0, 0);
        }
    }

    #pragma unroll
    for (int rt = 0; rt < 2; ++rt) {
        #pragma unroll
        for (int reg = 0; reg < 4; ++reg) {
            int grow = r0 + (w << 5) + (rt << 4) + (kg << 2) + reg;
            if (grow < n_nodes) {
                float ns = nsf[grow];
                #pragma unroll
                for (int ct = 0; ct < 4; ++ct) {
                    int colp = ((ct & 1) << 4) + l16;
                    __half* hp = h + (size_t)(ct >> 1) * plane_elems + ((size_t)grow << 5) + colp;
                    *hp = __float2half(acc[rt][ct][reg] * ns);
                }
            }
        }
    }
}

// ---------------- gather ONE 32-col plane (8 lanes/edge, uint2, unroll 2) ----------------
__global__ __launch_bounds__(256) void gather_kernel(
    const __half* __restrict__ h, const int* __restrict__ rowptr,
    const unsigned short* __restrict__ col, const float* __restrict__ bias,
    float* __restrict__ out, int n_nodes, size_t plane_elems, int plane)
{
    int wid = (blockIdx.x * blockDim.x + threadIdx.x) >> 6;
    int lane = threadIdx.x & 63;
    if (wid >= n_nodes) return;
    const int g = lane >> 3, l8 = lane & 7;

    const int beg = rowptr[wid];
    const int end = rowptr[wid + 1];
    const int deg = end - beg;

    const char* hbase = (const char*)(h + (size_t)plane * plane_elems) + (l8 << 3);

    float4 acc = make_float4(0.f, 0.f, 0.f, 0.f);
    #pragma unroll 2
    for (int i = beg + g; i < end; i += 8) {
        int s = col[i];
        uint2 v = *(const uint2*)(hbase + ((size_t)s << 6));
        __half2 p0 = *(__half2*)&v.x;
        __half2 p1 = *(__half2*)&v.y;
        float2 a = __half22float2(p0);
        float2 b2 = __half22float2(p1);
        acc.x += a.x; acc.y += a.y; acc.z += b2.x; acc.w += b2.y;
    }

    #pragma unroll
    for (int d = 8; d <= 32; d <<= 1) {
        acc.x += __shfl_xor(acc.x, d, 64);
        acc.y += __shfl_xor(acc.y, d, 64);
        acc.z += __shfl_xor(acc.z, d, 64);
        acc.w += __shfl_xor(acc.w, d, 64);
    }

    if (g == 0) {
        float nd = rsqrtf(fmaxf((float)deg, 1.0f));
        int c0 = (plane << 5) + (l8 << 2);
        float4 bb = *(const float4*)(&bias[c0]);
        float4 o;
        o.x = fmaxf(fmaf(acc.x, nd, bb.x), 0.f);
        o.y = fmaxf(fmaf(acc.y, nd, bb.y), 0.f);
        o.z = fmaxf(fmaf(acc.z, nd, bb.z), 0.f);
        o.w = fmaxf(fmaf(acc.w, nd, bb.w), 0.f);
        *(float4*)(&out[((size_t)wid << 6) + c0]) = o;
    }
}

extern "C" void kernel_launch(void* const* d_in, const int* in_sizes, int n_in,
                              void* d_out, int out_size, void* d_ws, size_t ws_size,
                              hipStream_t stream) {
    const float* x   = (const float*)d_in[0];
    const float* W   = (const float*)d_in[1];
    const float* b   = (const float*)d_in[2];
    const int*   src = (const int*)d_in[3];
    const int*   dst = (const int*)d_in[4];
    float* out = (float*)d_out;

    const int n_nodes = in_sizes[0] / DIN;   // 50000
    const int n_edges = in_sizes[3];         // 800000
    const int nb = (n_nodes + 511) / 512;                        // 98
    const int nbuck = (n_nodes + BUCKET - 1) >> BUCKET_BITS;     // 4
    const int npair = (nbuck + 1) >> 1;                          // 2
    const int n_pad = ((n_nodes + 63) / 64) * 64;                // 50048
    const size_t plane_elems = (size_t)n_pad * 32;               // halves per plane

    // workspace layout
    float* nsf  = (float*)d_ws;                 // n
    int* indeg  = (int*)(nsf + n_nodes);        // n_pad (pair reads safe)
    int* rowptr = indeg + n_pad;                // n+1
    int* bsum   = rowptr + n_nodes + 1;         // 128
    unsigned short* w16t = (unsigned short*)(bsum + 128);    // 16384 u16
    size_t off = (size_t)((char*)(w16t + 16384) - (char*)d_ws);
    off = (off + 63) / 64 * 64;
    unsigned int* epack = (unsigned int*)((char*)d_ws + off);        // n_edges u32
    off += (((size_t)n_edges * 4 + 63) / 64) * 64;
    unsigned short* col = (unsigned short*)((char*)d_ws + off);      // n_edges u16
    off += (((size_t)n_edges * 2 + 63) / 64) * 64;
    unsigned short* part = (unsigned short*)((char*)d_ws + off);     // 2*CHUNKS*n_pad u16
    off += (((size_t)2 * CHUNKS * n_pad * 2 + 63) / 64) * 64;
    __half* h = (__half*)((char*)d_ws + off);                        // 2 planes x n_pad x 32

    hist_kernel<<<dim3(CHUNKS, npair, 2), 256, 0, stream>>>(src, dst, part, epack, n_nodes, n_edges, n_pad);
    reduce_pair_kernel<<<nb + 64, 256, 0, stream>>>(part, nsf, indeg, bsum, n_nodes, n_pad, nb, W, w16t);
    emit_pair_kernel<<<nb, 256, 0, stream>>>(indeg, bsum, rowptr, n_nodes, n_edges, nb);
    fill_kernel<<<dim3(CHUNKS, nbuck), 256, 0, stream>>>(epack, part, rowptr, col, n_nodes, n_edges, n_pad);
    gemm_mfma_kernel<<<(n_nodes + BM - 1) / BM, 256, 0, stream>>>(x, w16t, nsf, h, n_nodes, plane_elems);
    gather_kernel<<<((size_t)n_nodes * 64 + 255) / 256, 256, 0, stream>>>(h, rowptr, col, b, out, n_nodes, plane_elems, 0);
    gather_kernel<<<((size_t)n_nodes * 64 + 255) / 256, 256, 0, stream>>>(h, rowptr, col, b, out, n_nodes, plane_elems, 1);
}